// Round 3
// baseline (212.436 us; speedup 1.0000x reference)
//
#include <hip/hip_runtime.h>
#include <hip/hip_fp16.h>
#include <cstddef>

#define N_ 1024
#define M_ 1024
#define D_ 1024
#define G_ 16
#define DG_ 64

typedef __bf16 bf16x8 __attribute__((ext_vector_type(8)));
typedef _Float16 f16x8 __attribute__((ext_vector_type(8)));
typedef float f32x4 __attribute__((ext_vector_type(4)));

// ---------------------------------------------------------------------------
// Transpose-cast: WqT/WkT[j][d] = (bf16) W[d][j].  64x64 tiles.
// ---------------------------------------------------------------------------
__global__ __launch_bounds__(256)
void transpose_cast(const float* __restrict__ Wq, const float* __restrict__ Wk,
                    __bf16* __restrict__ WqT, __bf16* __restrict__ WkT)
{
    __shared__ float t[64][65];
    const float* src = blockIdx.z ? Wk : Wq;
    __bf16* dst = blockIdx.z ? WkT : WqT;
    const int i0 = blockIdx.x * 64, j0 = blockIdx.y * 64;
    const int tid = threadIdx.x;
    const int r = tid >> 4, c4 = (tid & 15) * 4;
    #pragma unroll
    for (int it = 0; it < 4; ++it) {
        float4 a = *(const float4*)&src[(size_t)(i0 + r + it * 16) * D_ + j0 + c4];
        t[r + it * 16][c4 + 0] = a.x; t[r + it * 16][c4 + 1] = a.y;
        t[r + it * 16][c4 + 2] = a.z; t[r + it * 16][c4 + 3] = a.w;
    }
    __syncthreads();
    #pragma unroll
    for (int it = 0; it < 4; ++it) {
        const int row = r + it * 16;   // j within tile
        __bf16 p[4];
        #pragma unroll
        for (int q = 0; q < 4; ++q) p[q] = (__bf16)t[c4 + q][row];
        *(uint2*)&dst[(size_t)(j0 + row) * D_ + i0 + c4] = *(const uint2*)p;
    }
}

// Plain cast for Wv (already [go][d] = B^T layout).
__global__ __launch_bounds__(256)
void cast_wv(const float* __restrict__ Wv, __bf16* __restrict__ out)
{
    const int idx = blockIdx.x * 256 + threadIdx.x;
    float4 a = *(const float4*)&Wv[(size_t)idx * 4];
    __bf16 p[4] = {(__bf16)a.x, (__bf16)a.y, (__bf16)a.z, (__bf16)a.w};
    *(uint2*)&out[(size_t)idx * 4] = *(const uint2*)p;
}

// ---------------------------------------------------------------------------
// Fused MFMA GEMM, 128x128 tile, BK=64, 4 waves of 64x64 (4x4 MFMA tiles).
// z=0: q_bf[n][go] = bf16((roi@Wq + bq)*0.125)
// z=1: k_bf[m][go] = bf16(ref@Wk + bk)
// z=2: Vt_bf[go][m] = bf16(ref@Wv^T)   (stored transposed)
// ---------------------------------------------------------------------------
__global__ __launch_bounds__(256)
void gemm_mfma(const float* __restrict__ roi, const float* __restrict__ ref,
               const __bf16* __restrict__ WqT, const __bf16* __restrict__ WkT,
               const __bf16* __restrict__ Wvb,
               const float* __restrict__ bq, const float* __restrict__ bk,
               __bf16* __restrict__ qout, __bf16* __restrict__ kout,
               __bf16* __restrict__ Vt)
{
    __shared__ __bf16 As[128][72];
    __shared__ __bf16 Bs[128][72];
    const int z = blockIdx.z;
    const float* A = (z == 0) ? roi : ref;
    const __bf16* B = (z == 0) ? WqT : (z == 1) ? WkT : Wvb;
    const int tid = threadIdx.x;
    const int i0 = blockIdx.x * 128, j0 = blockIdx.y * 128;
    const int w = tid >> 6, lane = tid & 63;
    const int quad = lane >> 4, l15 = lane & 15;
    const int iw = (w & 1) * 64, jw = (w >> 1) * 64;

    f32x4 acc[4][4] = {};

    for (int k0 = 0; k0 < D_; k0 += 64) {
        __syncthreads();
        #pragma unroll
        for (int it = 0; it < 8; ++it) {
            const int idx = tid + 256 * it;
            const int row = idx >> 4, c = idx & 15;
            float4 a = *(const float4*)&A[(size_t)(i0 + row) * D_ + k0 + c * 4];
            __bf16* d = &As[row][c * 4];
            d[0] = (__bf16)a.x; d[1] = (__bf16)a.y; d[2] = (__bf16)a.z; d[3] = (__bf16)a.w;
        }
        #pragma unroll
        for (int it = 0; it < 4; ++it) {
            const int idx = tid + 256 * it;
            const int row = idx >> 3, c = idx & 7;
            *(uint4*)&Bs[row][c * 8] = *(const uint4*)&B[(size_t)(j0 + row) * D_ + k0 + c * 8];
        }
        __syncthreads();
        #pragma unroll
        for (int ks = 0; ks < 2; ++ks) {
            bf16x8 af[4], bfr[4];
            #pragma unroll
            for (int t = 0; t < 4; ++t) {
                af[t]  = *(const bf16x8*)&As[iw + t * 16 + l15][ks * 32 + quad * 8];
                bfr[t] = *(const bf16x8*)&Bs[jw + t * 16 + l15][ks * 32 + quad * 8];
            }
            #pragma unroll
            for (int ti = 0; ti < 4; ++ti)
                #pragma unroll
                for (int tj = 0; tj < 4; ++tj)
                    acc[ti][tj] = __builtin_amdgcn_mfma_f32_16x16x32_bf16(
                        af[ti], bfr[tj], acc[ti][tj], 0, 0, 0);
        }
    }

    if (z < 2) {
        const float* bias = (z == 0) ? bq : bk;
        __bf16* out = (z == 0) ? qout : kout;
        const float scale = (z == 0) ? 0.125f : 1.0f;
        #pragma unroll
        for (int ti = 0; ti < 4; ++ti)
            #pragma unroll
            for (int tj = 0; tj < 4; ++tj) {
                const int col = j0 + jw + tj * 16 + l15;
                const float bb = bias[col];
                #pragma unroll
                for (int r = 0; r < 4; ++r) {
                    const int rowi = i0 + iw + ti * 16 + quad * 4 + r;
                    out[(size_t)rowi * D_ + col] = (__bf16)((acc[ti][tj][r] + bb) * scale);
                }
            }
    } else {
        #pragma unroll
        for (int ti = 0; ti < 4; ++ti)
            #pragma unroll
            for (int tj = 0; tj < 4; ++tj) {
                const int col = j0 + jw + tj * 16 + l15;        // go
                const int row0 = i0 + iw + ti * 16 + quad * 4;  // m base
                __bf16 p[4];
                #pragma unroll
                for (int r = 0; r < 4; ++r) p[r] = (__bf16)acc[ti][tj][r];
                *(uint2*)&Vt[(size_t)col * M_ + row0] = *(const uint2*)p;
            }
    }
}

// ---------------------------------------------------------------------------
// Positional affinity via MFMA f16: A = emb (16 pairs x 64), B = Wg (16 g x 64).
// Each lane builds its 8-element A-fragment: k = ks*32 + quad*8 + j maps to
// feature f = k>>4, sin if (k&15)<8 else cos (= sin(t + pi/2)).
// aw[g][n][m] = fp16( relu(emb.Wg[g] + bg[g]) + 1e-6 )
// ---------------------------------------------------------------------------
__global__ __launch_bounds__(256)
void posbias_mfma(const float* __restrict__ rois1, const float* __restrict__ rois2,
                  const float* __restrict__ Wg, const float* __restrict__ bg,
                  __half* __restrict__ aw)
{
    const int tid = threadIdx.x;
    const int w = tid >> 6, lane = tid & 63;
    const int quad = lane >> 4, l15 = lane & 15;
    const int n = blockIdx.y;
    const int m0w = blockIdx.x * 256 + w * 64;   // wave covers m0w .. m0w+63

    // n-side box (uniform -> scalar)
    const float xmin = rois1[n * 4 + 0], ymin = rois1[n * 4 + 1];
    const float xmax = rois1[n * 4 + 2], ymax = rois1[n * 4 + 3];
    const float wn  = xmax - xmin + 1.f, hn  = ymax - ymin + 1.f;
    const float cxn = 0.5f * (xmin + xmax), cyn = 0.5f * (ymin + ymax);

    // Wg B-fragment (g = l15), cast to f16
    f16x8 wgf[2];
    #pragma unroll
    for (int ks = 0; ks < 2; ++ks) {
        const float* p = &Wg[l15 * 64 + ks * 32 + quad * 8];
        float4 a = *(const float4*)p;
        float4 b = *(const float4*)(p + 4);
        wgf[ks][0] = (_Float16)a.x; wgf[ks][1] = (_Float16)a.y;
        wgf[ks][2] = (_Float16)a.z; wgf[ks][3] = (_Float16)a.w;
        wgf[ks][4] = (_Float16)b.x; wgf[ks][5] = (_Float16)b.y;
        wgf[ks][6] = (_Float16)b.z; wgf[ks][7] = (_Float16)b.w;
    }
    const float bgv = bg[l15];

    const float fr8[8] = {100.0f, 42.16965f, 17.782794f, 7.4989421f,
                          3.1622777f, 1.3335214f, 0.56234133f, 0.23713737f};
    const float phase = (quad & 1) ? 1.5707963267948966f : 0.f;

    #pragma unroll
    for (int ti = 0; ti < 4; ++ti) {
        const int mt0 = m0w + ti * 16;
        const int m = mt0 + l15;
        float4 r2 = *(const float4*)&rois2[m * 4];
        const float wr  = r2.z - r2.x + 1.f, hr  = r2.w - r2.y + 1.f;
        const float cxr = 0.5f * (r2.x + r2.z), cyr = 0.5f * (r2.y + r2.w);

        const float f0 = __logf(fabsf((cxn - cxr) / wn) + 0.001f);
        const float f1 = __logf(fabsf((cyn - cyr) / hn) + 0.001f);
        const float f2 = __logf(wn / wr);
        const float f3 = __logf(hn / hr);
        const float fa = (quad & 2) ? f1 : f0;   // ks=0: f0 (quad 0,1), f1 (quad 2,3)
        const float fb = (quad & 2) ? f3 : f2;   // ks=1: f2, f3

        f32x4 acc = {};
        #pragma unroll
        for (int ks = 0; ks < 2; ++ks) {
            const float feat = ks ? fb : fa;
            f16x8 ef;
            #pragma unroll
            for (int j = 0; j < 8; ++j)
                ef[j] = (_Float16)__sinf(fmaf(feat, fr8[j], phase));
            acc = __builtin_amdgcn_mfma_f32_16x16x32_f16(ef, wgf[ks], acc, 0, 0, 0);
        }

        // D: row = pair (quad*4+r), col = g (l15). 4 consecutive m -> one 8B store.
        __half p[4];
        #pragma unroll
        for (int r = 0; r < 4; ++r)
            p[r] = __float2half(fmaxf(acc[r] + bgv, 0.f) + 1e-6f);
        *(uint2*)&aw[(size_t)l15 * N_ * M_ + (size_t)n * M_ + mt0 + quad * 4] =
            *(const uint2*)p;
    }
}

// ---------------------------------------------------------------------------
// MFMA flash attention, no max-tracking (|s| <= ~5 -> exp safe), deferred
// l-reduction, register-pipelined K/V/AW staging.
// ---------------------------------------------------------------------------
__global__ __launch_bounds__(256)
void attn_mfma(const __bf16* __restrict__ qb, const __bf16* __restrict__ kb,
               const __bf16* __restrict__ Vt, const __half* __restrict__ aw,
               const float* __restrict__ bv, float* __restrict__ out)
{
    __shared__ __bf16 qs[64][72];
    __shared__ __bf16 Ks[64][72];
    __shared__ __bf16 Vs[64][72];   // [o][m]
    __shared__ __bf16 Ps[64][72];   // [n][m] wave-private bands
    __shared__ __half AWs[64][72];

    const int tid = threadIdx.x;
    const int w = tid >> 6, lane = tid & 63;
    const int quad = lane >> 4, l15 = lane & 15;
    const int n0 = blockIdx.x * 64, g = blockIdx.y;

    const int srow = tid >> 3, scol = (tid & 7) * 8;   // staging coords (rows 0..31 per it)

    #pragma unroll
    for (int it = 0; it < 2; ++it) {
        const int row = srow + it * 32;
        *(uint4*)&qs[row][scol] = *(const uint4*)&qb[(size_t)(n0 + row) * D_ + g * 64 + scol];
    }

    uint4 rK[2], rV[2], rA[2];
    {
        #pragma unroll
        for (int it = 0; it < 2; ++it) {
            const int row = srow + it * 32;
            rK[it] = *(const uint4*)&kb[(size_t)row * D_ + g * 64 + scol];
            rV[it] = *(const uint4*)&Vt[(size_t)(g * 64 + row) * M_ + scol];
            rA[it] = *(const uint4*)&aw[((size_t)g * N_ + n0 + row) * M_ + scol];
        }
    }

    f32x4 acc[4] = {};
    float lsum[4] = {0.f, 0.f, 0.f, 0.f};
    float bvv[4];
    #pragma unroll
    for (int t = 0; t < 4; ++t) bvv[t] = bv[g * 64 + t * 16 + l15];

    for (int mt = 0; mt < 16; ++mt) {
        __syncthreads();   // previous tile's consumers done
        #pragma unroll
        for (int it = 0; it < 2; ++it) {
            const int row = srow + it * 32;
            *(uint4*)&Ks[row][scol]  = rK[it];
            *(uint4*)&Vs[row][scol]  = rV[it];
            *(uint4*)&AWs[row][scol] = rA[it];
        }
        __syncthreads();

        if (mt < 15) {
            const int m0n = (mt + 1) * 64;
            #pragma unroll
            for (int it = 0; it < 2; ++it) {
                const int row = srow + it * 32;
                rK[it] = *(const uint4*)&kb[(size_t)(m0n + row) * D_ + g * 64 + scol];
                rV[it] = *(const uint4*)&Vt[(size_t)(g * 64 + row) * M_ + m0n + scol];
                rA[it] = *(const uint4*)&aw[((size_t)g * N_ + n0 + row) * M_ + m0n + scol];
            }
        }

        // ---- S = q k^T ----
        f32x4 s[4] = {};
        #pragma unroll
        for (int ks = 0; ks < 2; ++ks) {
            bf16x8 a = *(const bf16x8*)&qs[w * 16 + l15][ks * 32 + quad * 8];
            #pragma unroll
            for (int t = 0; t < 4; ++t) {
                bf16x8 b = *(const bf16x8*)&Ks[t * 16 + l15][ks * 32 + quad * 8];
                s[t] = __builtin_amdgcn_mfma_f32_16x16x32_bf16(a, b, s[t], 0, 0, 0);
            }
        }

        // ---- p = aw * exp(s); accumulate partial l; stage P (wave-private) ----
        #pragma unroll
        for (int t = 0; t < 4; ++t)
            #pragma unroll
            for (int r = 0; r < 4; ++r) {
                const float e = __expf(s[t][r]);
                const float p = __half2float(AWs[w * 16 + quad * 4 + r][t * 16 + l15]) * e;
                lsum[r] += p;
                Ps[w * 16 + quad * 4 + r][t * 16 + l15] = (__bf16)p;
            }

        // ---- acc += P V ----
        #pragma unroll
        for (int ks = 0; ks < 2; ++ks) {
            bf16x8 a = *(const bf16x8*)&Ps[w * 16 + l15][ks * 32 + quad * 8];
            #pragma unroll
            for (int t = 0; t < 4; ++t) {
                bf16x8 b = *(const bf16x8*)&Vs[t * 16 + l15][ks * 32 + quad * 8];
                acc[t] = __builtin_amdgcn_mfma_f32_16x16x32_bf16(a, b, acc[t], 0, 0, 0);
            }
        }
    }

    // final l reduction across the 16 column-lanes of each quad group
    #pragma unroll
    for (int r = 0; r < 4; ++r) {
        #pragma unroll
        for (int d = 1; d < 16; d <<= 1)
            lsum[r] += __shfl_xor(lsum[r], d, 64);
        lsum[r] = 1.f / lsum[r];
    }

    #pragma unroll
    for (int r = 0; r < 4; ++r) {
        const int nrow = n0 + w * 16 + quad * 4 + r;
        #pragma unroll
        for (int t = 0; t < 4; ++t)
            out[(size_t)nrow * D_ + g * 64 + t * 16 + l15] = acc[t][r] * lsum[r] + bvv[t];
    }
}

extern "C" void kernel_launch(void* const* d_in, const int* in_sizes, int n_in,
                              void* d_out, int out_size, void* d_ws, size_t ws_size,
                              hipStream_t stream) {
    const float* roi_feat = (const float*)d_in[0];
    const float* ref_feat = (const float*)d_in[1];
    const float* rois1    = (const float*)d_in[2];
    const float* rois2    = (const float*)d_in[3];
    const float* Wq       = (const float*)d_in[4];
    const float* bq       = (const float*)d_in[5];
    const float* Wk       = (const float*)d_in[6];
    const float* bk       = (const float*)d_in[7];
    const float* Wg       = (const float*)d_in[8];
    const float* bg       = (const float*)d_in[9];
    const float* Wv       = (const float*)d_in[10];
    const float* bv       = (const float*)d_in[11];
    float* out = (float*)d_out;

    char* ws = (char*)d_ws;
    __bf16* WqT  = (__bf16*)(ws + 0);
    __bf16* WkT  = (__bf16*)(ws + (2u << 20));
    __bf16* Wvb  = (__bf16*)(ws + (4u << 20));
    __bf16* qbuf = (__bf16*)(ws + (6u << 20));
    __bf16* kbuf = (__bf16*)(ws + (8u << 20));
    __bf16* Vtb  = (__bf16*)(ws + (10u << 20));
    __half* aw   = (__half*)(ws + (12u << 20));

    dim3 blk(256);
    transpose_cast<<<dim3(16, 16, 2), blk, 0, stream>>>(Wq, Wk, WqT, WkT);
    cast_wv<<<dim3(1024), blk, 0, stream>>>(Wv, Wvb);
    posbias_mfma<<<dim3(4, 1024), blk, 0, stream>>>(rois1, rois2, Wg, bg, aw);
    gemm_mfma<<<dim3(8, 8, 3), blk, 0, stream>>>(roi_feat, ref_feat, WqT, WkT, Wvb,
                                                 bq, bk, qbuf, kbuf, Vtb);
    attn_mfma<<<dim3(16, 16), blk, 0, stream>>>(qbuf, kbuf, Vtb, aw, bv, out);
}

// Round 4
// 162.958 us; speedup vs baseline: 1.3036x; 1.3036x over previous
//
#include <hip/hip_runtime.h>
#include <hip/hip_fp16.h>
#include <cstddef>

#define N_ 1024
#define M_ 1024
#define D_ 1024
#define G_ 16
#define DG_ 64

typedef __bf16 bf16x8 __attribute__((ext_vector_type(8)));
typedef _Float16 f16x8 __attribute__((ext_vector_type(8)));
typedef float f32x4 __attribute__((ext_vector_type(4)));

// Fragment-major layout helpers.
// Qf/Kf: b/a-operand frags for S^T MFMA: [g][rb(64)][ks(2)][lane(64)][8]
//   element = row(rb*16 + lane&15), k = ks*32 + (lane>>4)*8 + j   (k = go%64)
__device__ __forceinline__ size_t qkf_idx(int g, int rb, int ks, int lane) {
    return ((((size_t)(g * 64 + rb)) * 2 + ks) * 64 + lane) * 8;
}
// Vf: a-operand frags for (PV)^T: [g][ot(4)][mc(32)][lane(64)][8]
//   element = V[m = mc*32 + (lane>>4)*8 + j][o = g*64 + ot*16 + (lane&15)]
__device__ __forceinline__ size_t vf_idx(int g, int ot, int mc, int lane) {
    return ((((size_t)(g * 4 + ot)) * 32 + mc) * 64 + lane) * 8;
}
// AWt: matches S^T C-layout: [g][mb(64)][n(1024)][16]  (16 = quad*4 + r, the m%16)
__device__ __forceinline__ size_t awt_idx(int g, int mb, int n, int quad) {
    return (((size_t)(g * 64 + mb)) * 1024 + n) * 16 + quad * 4;
}

// ---------------------------------------------------------------------------
// Transpose-cast: WqT/WkT[j][d] = (bf16) W[d][j].  64x64 tiles.
// ---------------------------------------------------------------------------
__global__ __launch_bounds__(256)
void transpose_cast(const float* __restrict__ Wq, const float* __restrict__ Wk,
                    __bf16* __restrict__ WqT, __bf16* __restrict__ WkT)
{
    __shared__ float t[64][65];
    const float* src = blockIdx.z ? Wk : Wq;
    __bf16* dst = blockIdx.z ? WkT : WqT;
    const int i0 = blockIdx.x * 64, j0 = blockIdx.y * 64;
    const int tid = threadIdx.x;
    const int r = tid >> 4, c4 = (tid & 15) * 4;
    #pragma unroll
    for (int it = 0; it < 4; ++it) {
        float4 a = *(const float4*)&src[(size_t)(i0 + r + it * 16) * D_ + j0 + c4];
        t[r + it * 16][c4 + 0] = a.x; t[r + it * 16][c4 + 1] = a.y;
        t[r + it * 16][c4 + 2] = a.z; t[r + it * 16][c4 + 3] = a.w;
    }
    __syncthreads();
    #pragma unroll
    for (int it = 0; it < 4; ++it) {
        const int row = r + it * 16;
        __bf16 p[4];
        #pragma unroll
        for (int q = 0; q < 4; ++q) p[q] = (__bf16)t[c4 + q][row];
        *(uint2*)&dst[(size_t)(j0 + row) * D_ + i0 + c4] = *(const uint2*)p;
    }
}

__global__ __launch_bounds__(256)
void cast_wv(const float* __restrict__ Wv, __bf16* __restrict__ out)
{
    const int idx = blockIdx.x * 256 + threadIdx.x;
    float4 a = *(const float4*)&Wv[(size_t)idx * 4];
    __bf16 p[4] = {(__bf16)a.x, (__bf16)a.y, (__bf16)a.z, (__bf16)a.w};
    *(uint2*)&out[(size_t)idx * 4] = *(const uint2*)p;
}

// ---------------------------------------------------------------------------
// Fused MFMA GEMM, 128x128 tile, BK=64. Epilogues write fragment-major bufs:
// z=0: Qf = frag((roi@Wq + bq)*0.125) ; z=1: Kf = frag(ref@Wk + bk)
// z=2: Vf = frag(ref@Wv^T)
// ---------------------------------------------------------------------------
__global__ __launch_bounds__(256)
void gemm_mfma(const float* __restrict__ roi, const float* __restrict__ ref,
               const __bf16* __restrict__ WqT, const __bf16* __restrict__ WkT,
               const __bf16* __restrict__ Wvb,
               const float* __restrict__ bq, const float* __restrict__ bk,
               __bf16* __restrict__ Qf, __bf16* __restrict__ Kf,
               __bf16* __restrict__ Vf)
{
    __shared__ __bf16 As[128][72];
    __shared__ __bf16 Bs[128][72];
    const int z = blockIdx.z;
    const float* A = (z == 0) ? roi : ref;
    const __bf16* B = (z == 0) ? WqT : (z == 1) ? WkT : Wvb;
    const int tid = threadIdx.x;
    const int i0 = blockIdx.x * 128, j0 = blockIdx.y * 128;
    const int w = tid >> 6, lane = tid & 63;
    const int quad = lane >> 4, l15 = lane & 15;
    const int iw = (w & 1) * 64, jw = (w >> 1) * 64;

    f32x4 acc[4][4] = {};

    for (int k0 = 0; k0 < D_; k0 += 64) {
        __syncthreads();
        #pragma unroll
        for (int it = 0; it < 8; ++it) {
            const int idx = tid + 256 * it;
            const int row = idx >> 4, c = idx & 15;
            float4 a = *(const float4*)&A[(size_t)(i0 + row) * D_ + k0 + c * 4];
            __bf16* d = &As[row][c * 4];
            d[0] = (__bf16)a.x; d[1] = (__bf16)a.y; d[2] = (__bf16)a.z; d[3] = (__bf16)a.w;
        }
        #pragma unroll
        for (int it = 0; it < 4; ++it) {
            const int idx = tid + 256 * it;
            const int row = idx >> 3, c = idx & 7;
            *(uint4*)&Bs[row][c * 8] = *(const uint4*)&B[(size_t)(j0 + row) * D_ + k0 + c * 8];
        }
        __syncthreads();
        #pragma unroll
        for (int ks = 0; ks < 2; ++ks) {
            bf16x8 af[4], bfr[4];
            #pragma unroll
            for (int t = 0; t < 4; ++t) {
                af[t]  = *(const bf16x8*)&As[iw + t * 16 + l15][ks * 32 + quad * 8];
                bfr[t] = *(const bf16x8*)&Bs[jw + t * 16 + l15][ks * 32 + quad * 8];
            }
            #pragma unroll
            for (int ti = 0; ti < 4; ++ti)
                #pragma unroll
                for (int tj = 0; tj < 4; ++tj)
                    acc[ti][tj] = __builtin_amdgcn_mfma_f32_16x16x32_bf16(
                        af[ti], bfr[tj], acc[ti][tj], 0, 0, 0);
        }
    }

    if (z < 2) {
        const float* bias = (z == 0) ? bq : bk;
        __bf16* dst = (z == 0) ? Qf : Kf;
        const float scale = (z == 0) ? 0.125f : 1.0f;
        #pragma unroll
        for (int ti = 0; ti < 4; ++ti) {
            const int rbase = i0 + iw + ti * 16;       // row base (n or m), mult of 16
            const int rb = rbase >> 4;
            #pragma unroll
            for (int tj = 0; tj < 4; ++tj) {
                const int go = j0 + jw + tj * 16 + l15;
                const int g = go >> 6, ks = (go >> 5) & 1;
                const int lanef = ((go >> 3) & 3) * 16;  // quad' from k-dim
                const int jf = go & 7;
                const float bb = bias[go];
                __bf16* base = dst + qkf_idx(g, rb, ks, 0) + jf;
                #pragma unroll
                for (int r = 0; r < 4; ++r)
                    base[(size_t)(lanef + quad * 4 + r) * 8] =
                        (__bf16)((acc[ti][tj][r] + bb) * scale);
            }
        }
    } else {
        #pragma unroll
        for (int ti = 0; ti < 4; ++ti) {
            const int mbase = i0 + iw + ti * 16 + quad * 4;   // mult of 4
            const int mc = mbase >> 5, quadv = (mbase >> 3) & 3, jb = mbase & 7;
            #pragma unroll
            for (int tj = 0; tj < 4; ++tj) {
                const int go = j0 + jw + tj * 16 + l15;
                const int g = go >> 6, ot = (go >> 4) & 3, o15 = go & 15;
                __bf16 p[4];
                #pragma unroll
                for (int r = 0; r < 4; ++r) p[r] = (__bf16)acc[ti][tj][r];
                *(uint2*)&Vf[vf_idx(g, ot, mc, quadv * 16 + o15) + jb] = *(const uint2*)p;
            }
        }
    }
}

// ---------------------------------------------------------------------------
// Positional affinity via MFMA f16; stores into AWt fragment layout.
// aw[g][n][m] = fp16( relu(emb.Wg[g] + bg[g]) + 1e-6 )
// ---------------------------------------------------------------------------
__global__ __launch_bounds__(256)
void posbias_mfma(const float* __restrict__ rois1, const float* __restrict__ rois2,
                  const float* __restrict__ Wg, const float* __restrict__ bg,
                  __half* __restrict__ AWt)
{
    const int tid = threadIdx.x;
    const int w = tid >> 6, lane = tid & 63;
    const int quad = lane >> 4, l15 = lane & 15;
    const int n = blockIdx.y;
    const int m0w = blockIdx.x * 256 + w * 64;

    const float xmin = rois1[n * 4 + 0], ymin = rois1[n * 4 + 1];
    const float xmax = rois1[n * 4 + 2], ymax = rois1[n * 4 + 3];
    const float wn  = xmax - xmin + 1.f, hn  = ymax - ymin + 1.f;
    const float cxn = 0.5f * (xmin + xmax), cyn = 0.5f * (ymin + ymax);

    f16x8 wgf[2];
    #pragma unroll
    for (int ks = 0; ks < 2; ++ks) {
        const float* p = &Wg[l15 * 64 + ks * 32 + quad * 8];
        float4 a = *(const float4*)p;
        float4 b = *(const float4*)(p + 4);
        wgf[ks][0] = (_Float16)a.x; wgf[ks][1] = (_Float16)a.y;
        wgf[ks][2] = (_Float16)a.z; wgf[ks][3] = (_Float16)a.w;
        wgf[ks][4] = (_Float16)b.x; wgf[ks][5] = (_Float16)b.y;
        wgf[ks][6] = (_Float16)b.z; wgf[ks][7] = (_Float16)b.w;
    }
    const float bgv = bg[l15];

    const float fr8[8] = {100.0f, 42.16965f, 17.782794f, 7.4989421f,
                          3.1622777f, 1.3335214f, 0.56234133f, 0.23713737f};
    const float phase = (quad & 1) ? 1.5707963267948966f : 0.f;

    #pragma unroll
    for (int ti = 0; ti < 4; ++ti) {
        const int mt0 = m0w + ti * 16;
        const int m = mt0 + l15;
        float4 r2 = *(const float4*)&rois2[m * 4];
        const float wr  = r2.z - r2.x + 1.f, hr  = r2.w - r2.y + 1.f;
        const float cxr = 0.5f * (r2.x + r2.z), cyr = 0.5f * (r2.y + r2.w);

        const float f0 = __logf(fabsf((cxn - cxr) / wn) + 0.001f);
        const float f1 = __logf(fabsf((cyn - cyr) / hn) + 0.001f);
        const float f2 = __logf(wn / wr);
        const float f3 = __logf(hn / hr);
        const float fa = (quad & 2) ? f1 : f0;
        const float fb = (quad & 2) ? f3 : f2;

        f32x4 acc = {};
        #pragma unroll
        for (int ks = 0; ks < 2; ++ks) {
            const float feat = ks ? fb : fa;
            f16x8 ef;
            #pragma unroll
            for (int j = 0; j < 8; ++j)
                ef[j] = (_Float16)__sinf(fmaf(feat, fr8[j], phase));
            acc = __builtin_amdgcn_mfma_f32_16x16x32_f16(ef, wgf[ks], acc, 0, 0, 0);
        }

        // lane holds aw for g=l15, m = mt0 + quad*4 + r, fixed n.
        __half p[4];
        #pragma unroll
        for (int r = 0; r < 4; ++r)
            p[r] = __float2half(fmaxf(acc[r] + bgv, 0.f) + 1e-6f);
        *(uint2*)&AWt[awt_idx(l15, mt0 >> 4, n, quad)] = *(const uint2*)p;
    }
}

// ---------------------------------------------------------------------------
// Wave-autonomous MFMA attention. Block = (16-row n-band, g); 4 waves each own
// a 256-m chunk (no barriers in the loop); LDS combine at the end.
// S^T = K q^T (C-layout row=m, col=n); p = aw*exp(s); outT = V^T P^T.
// ---------------------------------------------------------------------------
__global__ __launch_bounds__(256)
void attn_mfma(const __bf16* __restrict__ Qf, const __bf16* __restrict__ Kf,
               const __bf16* __restrict__ Vf, const __half* __restrict__ AWt,
               const float* __restrict__ bv, float* __restrict__ out)
{
    __shared__ __bf16 Ps[4][2][16][72];   // [wave][buf][n][m-of-64]
    __shared__ float accb[4][64][17];     // [wave][o][n]
    __shared__ float lsb[4][16];

    const int tid = threadIdx.x;
    const int w = tid >> 6, lane = tid & 63;
    const int quad = lane >> 4, l15 = lane & 15;
    const int nb = blockIdx.x, n0 = nb * 16, g = blockIdx.y;

    bf16x8 qf[2];
    qf[0] = *(const bf16x8*)&Qf[qkf_idx(g, nb, 0, lane)];
    qf[1] = *(const bf16x8*)&Qf[qkf_idx(g, nb, 1, lane)];

    f32x4 acc[4] = {};
    float llocal = 0.f;

    #pragma unroll
    for (int t64 = 0; t64 < 4; ++t64) {
        const int mt = w * 4 + t64;          // 64-m tile index (0..15)
        const int buf = t64 & 1;

        // S^T: a = K frags (rows m), b = q frags (cols n)
        f32x4 s[4];
        #pragma unroll
        for (int t = 0; t < 4; ++t) {
            bf16x8 ka0 = *(const bf16x8*)&Kf[qkf_idx(g, mt * 4 + t, 0, lane)];
            bf16x8 ka1 = *(const bf16x8*)&Kf[qkf_idx(g, mt * 4 + t, 1, lane)];
            f32x4 z = {};
            z = __builtin_amdgcn_mfma_f32_16x16x32_bf16(ka0, qf[0], z, 0, 0, 0);
            s[t] = __builtin_amdgcn_mfma_f32_16x16x32_bf16(ka1, qf[1], z, 0, 0, 0);
        }

        // p = aw * exp(s)  (lane: m = t*16 + quad*4 + r, n = l15)
        #pragma unroll
        for (int t = 0; t < 4; ++t) {
            uint2 au = *(const uint2*)&AWt[awt_idx(g, mt * 4 + t, n0 + l15, quad)];
            const __half* a4 = (const __half*)&au;
            __bf16 pk[4];
            #pragma unroll
            for (int r = 0; r < 4; ++r) {
                const float p = __half2float(a4[r]) * __expf(s[t][r]);
                llocal += p;
                pk[r] = (__bf16)p;
            }
            *(uint2*)&Ps[w][buf][l15][t * 16 + quad * 4] = *(const uint2*)pk;
        }

        // outT += V^T P^T : a = V frags (rows o), b = P frags (cols n)
        #pragma unroll
        for (int mcl = 0; mcl < 2; ++mcl) {
            bf16x8 pb = *(const bf16x8*)&Ps[w][buf][l15][mcl * 32 + quad * 8];
            #pragma unroll
            for (int ot = 0; ot < 4; ++ot) {
                bf16x8 va = *(const bf16x8*)&Vf[vf_idx(g, ot, mt * 2 + mcl, lane)];
                acc[ot] = __builtin_amdgcn_mfma_f32_16x16x32_bf16(va, pb, acc[ot], 0, 0, 0);
            }
        }
    }

    // reduce l over quads (lane bits 4,5) -> per n=l15
    llocal += __shfl_xor(llocal, 16, 64);
    llocal += __shfl_xor(llocal, 32, 64);

    #pragma unroll
    for (int ot = 0; ot < 4; ++ot)
        #pragma unroll
        for (int r = 0; r < 4; ++r)
            accb[w][ot * 16 + quad * 4 + r][l15] = acc[ot][r];
    if (quad == 0) lsb[w][l15] = llocal;
    __syncthreads();

    const float lt = lsb[0][l15] + lsb[1][l15] + lsb[2][l15] + lsb[3][l15];
    const float inv = 1.f / lt;
    #pragma unroll
    for (int r = 0; r < 4; ++r) {
        const int o = w * 16 + quad * 4 + r;
        const int ogl = g * 64 + o;
        const float v = accb[0][o][l15] + accb[1][o][l15] +
                        accb[2][o][l15] + accb[3][o][l15];
        out[(size_t)(n0 + l15) * D_ + ogl] = v * inv + bv[ogl];
    }
}

extern "C" void kernel_launch(void* const* d_in, const int* in_sizes, int n_in,
                              void* d_out, int out_size, void* d_ws, size_t ws_size,
                              hipStream_t stream) {
    const float* roi_feat = (const float*)d_in[0];
    const float* ref_feat = (const float*)d_in[1];
    const float* rois1    = (const float*)d_in[2];
    const float* rois2    = (const float*)d_in[3];
    const float* Wq       = (const float*)d_in[4];
    const float* bq       = (const float*)d_in[5];
    const float* Wk       = (const float*)d_in[6];
    const float* bk       = (const float*)d_in[7];
    const float* Wg       = (const float*)d_in[8];
    const float* bg       = (const float*)d_in[9];
    const float* Wv       = (const float*)d_in[10];
    const float* bv       = (const float*)d_in[11];
    float* out = (float*)d_out;

    char* ws = (char*)d_ws;
    __bf16* WqT = (__bf16*)(ws + 0);
    __bf16* WkT = (__bf16*)(ws + (2u << 20));
    __bf16* Wvb = (__bf16*)(ws + (4u << 20));
    __bf16* Qf  = (__bf16*)(ws + (6u << 20));
    __bf16* Kf  = (__bf16*)(ws + (8u << 20));
    __bf16* Vf  = (__bf16*)(ws + (10u << 20));
    __half* AWt = (__half*)(ws + (12u << 20));

    dim3 blk(256);
    transpose_cast<<<dim3(16, 16, 2), blk, 0, stream>>>(Wq, Wk, WqT, WkT);
    cast_wv<<<dim3(1024), blk, 0, stream>>>(Wv, Wvb);
    posbias_mfma<<<dim3(4, 1024), blk, 0, stream>>>(rois1, rois2, Wg, bg, AWt);
    gemm_mfma<<<dim3(8, 8, 3), blk, 0, stream>>>(roi_feat, ref_feat, WqT, WkT, Wvb,
                                                 bq, bk, Qf, Kf, Vf);
    attn_mfma<<<dim3(64, 16), blk, 0, stream>>>(Qf, Kf, Vf, AWt, bv, out);
}